// Round 1
// baseline (926.213 us; speedup 1.0000x reference)
//
#include <hip/hip_runtime.h>

#define N_NODES 512
#define FDIM    3072
#define HEADS   4
#define HFD     12288        // HEADS*FDIM
#define E_IN    4096
#define E_TOT   4608         // E_IN + N self loops
#define EPSV    1e-5f
#define SLOPE   0.2f

typedef unsigned short u16;
typedef unsigned int   u32;

typedef short s16x8 __attribute__((ext_vector_type(8)));
typedef float f32x4 __attribute__((ext_vector_type(4)));

__device__ __forceinline__ u16 f2bf(float f){
  u32 u = __builtin_bit_cast(u32, f);
  u = (u + 0x7fffu + ((u >> 16) & 1u)) >> 16;
  return (u16)u;
}
__device__ __forceinline__ float bf2f(u16 h){
  return __builtin_bit_cast(float, ((u32)h) << 16);
}

// ---------------- fc1 (1x1 conv C=3) + BN1 -> hf bf16 [512][3072] ----------
__global__ void k_fc1(const float* __restrict__ x, const float* __restrict__ W,
                      const float* __restrict__ b, const float* __restrict__ g,
                      const float* __restrict__ bb, const float* __restrict__ m,
                      const float* __restrict__ v, u16* __restrict__ hf){
  int id = blockIdx.x * 256 + threadIdx.x;   // 0..524287
  int n = id >> 10, p = id & 1023;
  float x0 = x[n * FDIM + p];
  float x1 = x[n * FDIM + 1024 + p];
  float x2 = x[n * FDIM + 2048 + p];
#pragma unroll
  for (int c = 0; c < 3; ++c){
    float t = b[c] + W[c*3+0]*x0 + W[c*3+1]*x1 + W[c*3+2]*x2;
    float inv = g[c] * rsqrtf(v[c] + EPSV);
    float o = t * inv + (bb[c] - m[c] * inv);
    hf[n * FDIM + c * 1024 + p] = f2bf(o);
  }
}

// ---------------- big GEMM: hf[512x3072] @ [Wl|Wr][3072x24576] + bias ------
// BM=512 (full M -> weights streamed exactly once), BN=64, BK=32.
// 256 threads = 4 waves, wave tile 128x64 (8x4 tiles of 16x16x32 MFMA).
__global__ __launch_bounds__(256, 2) void k_gemm(
    const u16* __restrict__ hf, const float* __restrict__ Wl,
    const float* __restrict__ bl, const float* __restrict__ Wr,
    const float* __restrict__ br, u16* __restrict__ xl, u16* __restrict__ xr){
  __shared__ u16 As[512 * 40];   // 512 rows x 32 k (padded to 40) bf16
  __shared__ u16 Bs[64 * 40];    // 64 cols  x 32 k (padded to 40) bf16

  const int tid  = threadIdx.x;
  const int wave = tid >> 6, lane = tid & 63;
  const int quad = lane >> 4, l16 = lane & 15;
  const int n0 = blockIdx.x * 64;

  const float* Wg; const float* biasp; u16* outp; int cb;
  if (n0 < HFD){ Wg = Wl; biasp = bl; outp = xl; cb = n0; }
  else         { Wg = Wr; biasp = br; outp = xr; cb = n0 - HFD; }

  // A staging map: 2048 16B-chunks (512 rows x 4 chunks), 8 per thread
  int arow[8], ach[8];
#pragma unroll
  for (int j = 0; j < 8; ++j){ int gch = j * 256 + tid; arow[j] = gch >> 2; ach[j] = gch & 3; }

  // B staging map: thread -> (col n, k-half kh), 8 k's each
  const int bn = tid & 63, bkh = tid >> 6;
  const float* wbase = Wg + (size_t)(bkh * 8) * HFD + (cb + bn);

  f32x4 acc[8][4];
#pragma unroll
  for (int i = 0; i < 8; ++i)
#pragma unroll
    for (int j = 0; j < 4; ++j) acc[i][j] = (f32x4){0.f, 0.f, 0.f, 0.f};

  for (int ks = 0; ks < 96; ++ks){
    const int k0 = ks * 32;
    // global loads first (overlap with previous MFMA)
    uint4 av[8];
#pragma unroll
    for (int j = 0; j < 8; ++j)
      av[j] = *(const uint4*)(hf + arow[j] * FDIM + k0 + ach[j] * 8);
    float bv[8];
    const float* wp = wbase + (size_t)k0 * HFD;
#pragma unroll
    for (int j = 0; j < 8; ++j) bv[j] = wp[(size_t)j * HFD];

    __syncthreads();   // previous iteration's LDS reads done
#pragma unroll
    for (int j = 0; j < 8; ++j)
      *(uint4*)(As + arow[j] * 40 + ach[j] * 8) = av[j];
    u32 pk0 = (u32)f2bf(bv[0]) | ((u32)f2bf(bv[1]) << 16);
    u32 pk1 = (u32)f2bf(bv[2]) | ((u32)f2bf(bv[3]) << 16);
    u32 pk2 = (u32)f2bf(bv[4]) | ((u32)f2bf(bv[5]) << 16);
    u32 pk3 = (u32)f2bf(bv[6]) | ((u32)f2bf(bv[7]) << 16);
    *(uint4*)(Bs + bn * 40 + bkh * 8) = make_uint4(pk0, pk1, pk2, pk3);
    __syncthreads();   // staging visible

    s16x8 af[8], bfr[4];
#pragma unroll
    for (int i = 0; i < 8; ++i)
      af[i] = __builtin_bit_cast(s16x8,
                *(const uint4*)(As + (wave * 128 + i * 16 + l16) * 40 + quad * 8));
#pragma unroll
    for (int j = 0; j < 4; ++j)
      bfr[j] = __builtin_bit_cast(s16x8,
                *(const uint4*)(Bs + (j * 16 + l16) * 40 + quad * 8));
#pragma unroll
    for (int i = 0; i < 8; ++i)
#pragma unroll
      for (int j = 0; j < 4; ++j)
        acc[i][j] = __builtin_amdgcn_mfma_f32_16x16x32_bf16(af[i], bfr[j], acc[i][j], 0, 0, 0);
  }

  // epilogue: + bias, store bf16
  float bj[4];
#pragma unroll
  for (int j = 0; j < 4; ++j) bj[j] = biasp[cb + j * 16 + l16];
#pragma unroll
  for (int i = 0; i < 8; ++i){
    int mrow = wave * 128 + i * 16 + quad * 4;
#pragma unroll
    for (int r = 0; r < 4; ++r){
      u16* orow = outp + (size_t)(mrow + r) * HFD + cb + l16;
#pragma unroll
      for (int j = 0; j < 4; ++j)
        orow[j * 16] = f2bf(acc[i][j][r] + bj[j]);
    }
  }
}

// ---------------- GATv2 edge logits ----------------------------------------
// one block per edge, one wave per head
__global__ void k_logits(const int* __restrict__ ei, const u16* __restrict__ xl,
                         const u16* __restrict__ xr, const float* __restrict__ att,
                         float* __restrict__ logits){
  int e = blockIdx.x;
  int h = threadIdx.x >> 6, lane = threadIdx.x & 63;
  int s, d;
  if (e < E_IN){ s = ei[e]; d = ei[E_IN + e]; } else { s = e - E_IN; d = s; }
  const u16* xlp = xl + (size_t)s * HFD + h * FDIM;
  const u16* xrp = xr + (size_t)d * HFD + h * FDIM;
  const float* ap = att + h * FDIM;
  float acc = 0.f;
#pragma unroll
  for (int it = 0; it < 12; ++it){
    int f = it * 256 + lane * 4;
    ushort4 a = *(const ushort4*)(xlp + f);
    ushort4 b = *(const ushort4*)(xrp + f);
    float4  w = *(const float4*)(ap + f);
    float v0 = bf2f(a.x) + bf2f(b.x); v0 = v0 > 0.f ? v0 : SLOPE * v0;
    float v1 = bf2f(a.y) + bf2f(b.y); v1 = v1 > 0.f ? v1 : SLOPE * v1;
    float v2 = bf2f(a.z) + bf2f(b.z); v2 = v2 > 0.f ? v2 : SLOPE * v2;
    float v3 = bf2f(a.w) + bf2f(b.w); v3 = v3 > 0.f ? v3 : SLOPE * v3;
    acc += v0 * w.x + v1 * w.y + v2 * w.z + v3 * w.w;
  }
#pragma unroll
  for (int o = 32; o > 0; o >>= 1) acc += __shfl_down(acc, o);
  if (lane == 0) logits[e * 4 + h] = acc;
}

// ---------------- CSR build -------------------------------------------------
__global__ void k_count(const int* __restrict__ ei, int* __restrict__ cnt){
  int e = blockIdx.x * 256 + threadIdx.x;
  if (e >= E_TOT) return;
  int d = (e < E_IN) ? ei[E_IN + e] : (e - E_IN);
  atomicAdd(&cnt[d], 1);
}

__global__ void k_scan(const int* __restrict__ cnt, int* __restrict__ off,
                       int* __restrict__ cursor){
  __shared__ int s[512];
  int t = threadIdx.x;
  int v = cnt[t];
  s[t] = v;
  __syncthreads();
  for (int d = 1; d < 512; d <<= 1){
    int add = (t >= d) ? s[t - d] : 0;
    __syncthreads();
    s[t] += add;
    __syncthreads();
  }
  int exc = s[t] - v;
  off[t] = exc;
  cursor[t] = exc;
}

__global__ void k_scatter(const int* __restrict__ ei, int* __restrict__ cursor,
                          int* __restrict__ elist){
  int e = blockIdx.x * 256 + threadIdx.x;
  if (e >= E_TOT) return;
  int d = (e < E_IN) ? ei[E_IN + e] : (e - E_IN);
  int pos = atomicAdd(&cursor[d], 1);
  elist[pos] = e;
}

// ---------------- per-dst segment softmax -> alpha -------------------------
__global__ void k_softmax(const int* __restrict__ cnt, const int* __restrict__ off,
                          const int* __restrict__ elist, const float* __restrict__ logits,
                          float* __restrict__ alpha){
  int i = blockIdx.x;
  int lane = threadIdx.x;            // block of 64 = 1 wave
  int deg = cnt[i], st = off[i];
#pragma unroll
  for (int h = 0; h < 4; ++h){
    float mx = -1e30f;
    for (int j = lane; j < deg; j += 64){
      int e = elist[st + j];
      mx = fmaxf(mx, logits[e * 4 + h]);
    }
#pragma unroll
    for (int o = 32; o > 0; o >>= 1) mx = fmaxf(mx, __shfl_down(mx, o));
    mx = __shfl(mx, 0);
    float sm = 0.f;
    for (int j = lane; j < deg; j += 64){
      int e = elist[st + j];
      sm += __expf(logits[e * 4 + h] - mx);
    }
#pragma unroll
    for (int o = 32; o > 0; o >>= 1) sm += __shfl_down(sm, o);
    sm = __shfl(sm, 0);
    float rs = 1.f / sm;
    for (int j = lane; j < deg; j += 64){
      int e = elist[st + j];
      alpha[e * 4 + h] = __expf(logits[e * 4 + h] - mx) * rs;
    }
  }
}

// ---------------- aggregate: agg[dst][h][f] = sum alpha * xl[src] ----------
__global__ void k_agg(const int* __restrict__ ei, const int* __restrict__ cnt,
                      const int* __restrict__ off, const int* __restrict__ elist,
                      const float* __restrict__ alpha, const u16* __restrict__ xl,
                      float* __restrict__ agg){
  int b = blockIdx.x;
  int dst = b >> 2, h = b & 3;
  int deg = cnt[dst], st = off[dst];
  int t = threadIdx.x;
#pragma unroll
  for (int c = 0; c < 3; ++c){
    int f = c * 1024 + t * 4;
    float a0 = 0.f, a1 = 0.f, a2 = 0.f, a3 = 0.f;
    for (int j = 0; j < deg; ++j){
      int e = elist[st + j];
      int s = (e < E_IN) ? ei[e] : (e - E_IN);
      float al = alpha[e * 4 + h];
      ushort4 xv = *(const ushort4*)(xl + (size_t)s * HFD + h * FDIM + f);
      a0 += al * bf2f(xv.x);
      a1 += al * bf2f(xv.y);
      a2 += al * bf2f(xv.z);
      a3 += al * bf2f(xv.w);
    }
    float4* op = (float4*)(agg + (size_t)dst * HFD + h * FDIM + f);
    *op = make_float4(a0, a1, a2, a3);
  }
}

// ---------------- fc2+BN2+shortcut + FFN (fused epilogue) ------------------
__global__ void k_final(const float* __restrict__ agg, const float* __restrict__ gat_b,
                        const float* __restrict__ W2, const float* __restrict__ b2,
                        const float* __restrict__ g2, const float* __restrict__ bb2,
                        const float* __restrict__ m2, const float* __restrict__ v2,
                        const float* __restrict__ W3, const float* __restrict__ b3,
                        const float* __restrict__ g3, const float* __restrict__ bb3,
                        const float* __restrict__ m3, const float* __restrict__ v3,
                        const float* __restrict__ W4, const float* __restrict__ b4,
                        const float* __restrict__ g4, const float* __restrict__ bb4,
                        const float* __restrict__ m4, const float* __restrict__ v4,
                        const float* __restrict__ x, float* __restrict__ out){
  int id = blockIdx.x * 256 + threadIdx.x;
  int n = id >> 10, p = id & 1023;
  float a[12];
#pragma unroll
  for (int o = 0; o < 12; ++o)
    a[o] = agg[(size_t)n * HFD + o * 1024 + p] + gat_b[o * 1024 + p];
  float g[3];
#pragma unroll
  for (int c = 0; c < 3; ++c){
    float t = b2[c];
#pragma unroll
    for (int o = 0; o < 12; ++o) t += W2[c * 12 + o] * a[o];
    float inv = g2[c] * rsqrtf(v2[c] + EPSV);
    g[c] = t * inv + (bb2[c] - m2[c] * inv) + x[n * FDIM + c * 1024 + p];
  }
  float f1[3];
#pragma unroll
  for (int c = 0; c < 3; ++c){
    float t = b3[c] + W3[c*3+0]*g[0] + W3[c*3+1]*g[1] + W3[c*3+2]*g[2];
    float inv = g3[c] * rsqrtf(v3[c] + EPSV);
    float vv = t * inv + (bb3[c] - m3[c] * inv);
    f1[c] = fmaxf(vv, 0.f);
  }
#pragma unroll
  for (int c = 0; c < 3; ++c){
    float t = b4[c] + W4[c*3+0]*f1[0] + W4[c*3+1]*f1[1] + W4[c*3+2]*f1[2];
    float inv = g4[c] * rsqrtf(v4[c] + EPSV);
    out[n * FDIM + c * 1024 + p] = t * inv + (bb4[c] - m4[c] * inv) + g[c];
  }
}

extern "C" void kernel_launch(void* const* d_in, const int* in_sizes, int n_in,
                              void* d_out, int out_size, void* d_ws, size_t ws_size,
                              hipStream_t stream){
  (void)in_sizes; (void)n_in; (void)out_size; (void)ws_size;
  const float* x     = (const float*)d_in[0];
  const int*   ei    = (const int*)d_in[1];
  const float* fc1_W = (const float*)d_in[2];
  const float* fc1_b = (const float*)d_in[3];
  const float* bn1_g = (const float*)d_in[4];
  const float* bn1_b = (const float*)d_in[5];
  const float* bn1_m = (const float*)d_in[6];
  const float* bn1_v = (const float*)d_in[7];
  const float* Wl    = (const float*)d_in[8];
  const float* bl    = (const float*)d_in[9];
  const float* Wr    = (const float*)d_in[10];
  const float* br    = (const float*)d_in[11];
  const float* att   = (const float*)d_in[12];
  const float* gat_b = (const float*)d_in[13];
  const float* fc2_W = (const float*)d_in[14];
  const float* fc2_b = (const float*)d_in[15];
  const float* bn2_g = (const float*)d_in[16];
  const float* bn2_b = (const float*)d_in[17];
  const float* bn2_m = (const float*)d_in[18];
  const float* bn2_v = (const float*)d_in[19];
  const float* ffn1_W= (const float*)d_in[20];
  const float* ffn1_b= (const float*)d_in[21];
  const float* bnf1_g= (const float*)d_in[22];
  const float* bnf1_b= (const float*)d_in[23];
  const float* bnf1_m= (const float*)d_in[24];
  const float* bnf1_v= (const float*)d_in[25];
  const float* ffn2_W= (const float*)d_in[26];
  const float* ffn2_b= (const float*)d_in[27];
  const float* bnf2_g= (const float*)d_in[28];
  const float* bnf2_b= (const float*)d_in[29];
  const float* bnf2_m= (const float*)d_in[30];
  const float* bnf2_v= (const float*)d_in[31];

  char* w = (char*)d_ws;
  u16*   hf     = (u16*)(w);                    // 512*3072*2      = 3,145,728
  u16*   xl     = (u16*)(w + 3145728);          // 512*12288*2     = 12,582,912
  u16*   xr     = (u16*)(w + 15728640);         // 12,582,912
  float* logits = (float*)(w + 28311552);       // 4608*4*4        = 73,728
  float* alpha  = (float*)(w + 28385280);       // 73,728
  int*   cnt    = (int*)(w + 28459008);         // 2048
  int*   offp   = (int*)(w + 28461056);         // 2048
  int*   cursor = (int*)(w + 28463104);         // 2048
  int*   elist  = (int*)(w + 28465152);         // 18,432
  float* agg    = (float*)(w + 28483584);       // 512*12288*4     = 25,165,824

  hipMemsetAsync(cnt, 0, 2048, stream);

  k_fc1<<<2048, 256, 0, stream>>>(x, fc1_W, fc1_b, bn1_g, bn1_b, bn1_m, bn1_v, hf);
  k_gemm<<<384, 256, 0, stream>>>(hf, Wl, bl, Wr, br, xl, xr);
  k_logits<<<E_TOT, 256, 0, stream>>>(ei, xl, xr, att, logits);
  k_count<<<18, 256, 0, stream>>>(ei, cnt);
  k_scan<<<1, 512, 0, stream>>>(cnt, offp, cursor);
  k_scatter<<<18, 256, 0, stream>>>(ei, cursor, elist);
  k_softmax<<<512, 64, 0, stream>>>(cnt, offp, elist, logits, alpha);
  k_agg<<<2048, 256, 0, stream>>>(ei, cnt, offp, elist, alpha, xl, agg);
  k_final<<<2048, 256, 0, stream>>>(agg, gat_b, fc2_W, fc2_b, bn2_g, bn2_b, bn2_m, bn2_v,
                                    ffn1_W, ffn1_b, bnf1_g, bnf1_b, bnf1_m, bnf1_v,
                                    ffn2_W, ffn2_b, bnf2_g, bnf2_b, bnf2_m, bnf2_v,
                                    x, (float*)d_out);
}

// Round 2
// 553.407 us; speedup vs baseline: 1.6737x; 1.6737x over previous
//
#include <hip/hip_runtime.h>

#define N_NODES 512
#define FDIM    3072
#define HEADS   4
#define HFD     12288        // HEADS*FDIM
#define E_IN    4096
#define E_TOT   4608         // E_IN + N self loops
#define EPSV    1e-5f
#define SLOPE   0.2f

typedef unsigned short u16;
typedef unsigned int   u32;

typedef short s16x8 __attribute__((ext_vector_type(8)));
typedef float f32x4 __attribute__((ext_vector_type(4)));

__device__ __forceinline__ u16 f2bf(float f){
  u32 u = __builtin_bit_cast(u32, f);
  u = (u + 0x7fffu + ((u >> 16) & 1u)) >> 16;
  return (u16)u;
}
__device__ __forceinline__ float bf2f(u16 h){
  return __builtin_bit_cast(float, ((u32)h) << 16);
}
__device__ __forceinline__ float bflo(u32 p){
  return __builtin_bit_cast(float, p << 16);
}
__device__ __forceinline__ float bfhi(u32 p){
  return __builtin_bit_cast(float, p & 0xffff0000u);
}

// async global -> LDS, 16 bytes per lane, dest = wave-uniform base + lane*16
__device__ __forceinline__ void gl_lds16(const u16* g, u16* l){
  __builtin_amdgcn_global_load_lds(
      (const __attribute__((address_space(1))) unsigned int*)g,
      (__attribute__((address_space(3))) unsigned int*)l, 16, 0, 0);
}

// ---------------- fc1 (1x1 conv C=3) + BN1 -> hf bf16 [512][3072] ----------
__global__ void k_fc1(const float* __restrict__ x, const float* __restrict__ W,
                      const float* __restrict__ b, const float* __restrict__ g,
                      const float* __restrict__ bb, const float* __restrict__ m,
                      const float* __restrict__ v, u16* __restrict__ hf,
                      int* __restrict__ cnt){
  int id = blockIdx.x * 256 + threadIdx.x;   // 0..524287
  if (id < 512) cnt[id] = 0;                 // zero CSR counts (used later in stream order)
  int n = id >> 10, p = id & 1023;
  float x0 = x[n * FDIM + p];
  float x1 = x[n * FDIM + 1024 + p];
  float x2 = x[n * FDIM + 2048 + p];
#pragma unroll
  for (int c = 0; c < 3; ++c){
    float t = b[c] + W[c*3+0]*x0 + W[c*3+1]*x1 + W[c*3+2]*x2;
    float inv = g[c] * rsqrtf(v[c] + EPSV);
    float o = t * inv + (bb[c] - m[c] * inv);
    hf[n * FDIM + c * 1024 + p] = f2bf(o);
  }
}

// ---------------- big GEMM: hf[512x3072] @ [Wl|Wr][3072x24576] + bias ------
// BM=512 (weights stream from HBM exactly once), BN=64, BK=32, 256 thr.
// A staged via global_load_lds (async DMA, XOR-swizzled layout, no VGPR data),
// B prefetched one iteration ahead in 8 VGPRs, converted fp32->bf16 into LDS.
__global__ __launch_bounds__(256, 2) void k_gemm(
    const u16* __restrict__ hf, const float* __restrict__ Wl,
    const float* __restrict__ bl, const float* __restrict__ Wr,
    const float* __restrict__ br, u16* __restrict__ xl, u16* __restrict__ xr){
  __shared__ u16 As[512 * 32];   // 512 rows x 32 k bf16, 16B-chunk XOR swizzle, no pad
  __shared__ u16 Bs[64 * 40];    // 64 cols  x 32 k (padded to 40) bf16

  const int tid  = threadIdx.x;
  const int wave = tid >> 6, lane = tid & 63;
  const int quad = lane >> 4, l16 = lane & 15;
  const int n0 = blockIdx.x * 64;

  const float* Wg; const float* biasp; u16* outp; int cb;
  if (n0 < HFD){ Wg = Wl; biasp = bl; outp = xl; cb = n0; }
  else         { Wg = Wr; biasp = br; outp = xr; cb = n0 - HFD; }

  // A staging (async): instr i of wave w covers rows (w*8+i)*16 .. +15, all 4 chunks.
  // lane L: row = base + (L>>2), stores logical chunk kc = (L&3) ^ ((L>>3)&3) at pos L&3.
  const u16* ga = hf + (size_t)(wave * 128 + (lane >> 2)) * FDIM
                     + (((lane & 3) ^ ((lane >> 3) & 3)) << 3);
  u16* la = As + wave * 8 * 512;     // per-instr +512 u16 (1 KB)

  // B staging: thread -> (col bn, k-octet bkh), 8 k's each
  const int bn = tid & 63, bkh = tid >> 6;
  const float* gb = Wg + (size_t)bkh * 8 * HFD + (cb + bn);
  u16* wb = Bs + bn * 40 + bkh * 8;

  // fragment read pointers (loop-invariant)
  // A: row = wave*128 + i*16 + l16, logical chunk quad stored at pos quad ^ ((l16>>1)&3)
  const u16* raf = As + (size_t)(wave * 128 + l16) * 32 + ((quad ^ ((l16 >> 1) & 3)) << 3);
  const u16* rbf = Bs + l16 * 40 + quad * 8;

  f32x4 acc[8][4];
#pragma unroll
  for (int i = 0; i < 8; ++i)
#pragma unroll
    for (int j = 0; j < 4; ++j) acc[i][j] = (f32x4){0.f, 0.f, 0.f, 0.f};

  float bv[8];
#pragma unroll
  for (int j = 0; j < 8; ++j) bv[j] = gb[(size_t)j * HFD];

  for (int ks = 0; ks < 96; ++ks){
    __syncthreads();                 // prev tile's LDS reads done
    // async A tile -> LDS
#pragma unroll
    for (int i = 0; i < 8; ++i)
      gl_lds16(ga + (size_t)i * 16 * FDIM + ks * 32, la + i * 512);
    // convert prefetched B regs -> LDS bf16
    u32 pk0 = (u32)f2bf(bv[0]) | ((u32)f2bf(bv[1]) << 16);
    u32 pk1 = (u32)f2bf(bv[2]) | ((u32)f2bf(bv[3]) << 16);
    u32 pk2 = (u32)f2bf(bv[4]) | ((u32)f2bf(bv[5]) << 16);
    u32 pk3 = (u32)f2bf(bv[6]) | ((u32)f2bf(bv[7]) << 16);
    *(uint4*)wb = make_uint4(pk0, pk1, pk2, pk3);
    __syncthreads();                 // staging visible (drains DMA too)

    s16x8 af[8], bfr[4];
#pragma unroll
    for (int i = 0; i < 8; ++i)
      af[i] = __builtin_bit_cast(s16x8, *(const uint4*)(raf + i * 512));
#pragma unroll
    for (int j = 0; j < 4; ++j)
      bfr[j] = __builtin_bit_cast(s16x8, *(const uint4*)(rbf + j * 640));

    // prefetch next B tile into regs (hidden under MFMA phase)
    const int kn = (ks < 95 ? ks + 1 : ks) * 32;
#pragma unroll
    for (int j = 0; j < 8; ++j) bv[j] = gb[(size_t)(kn + j) * HFD];

#pragma unroll
    for (int i = 0; i < 8; ++i)
#pragma unroll
      for (int j = 0; j < 4; ++j)
        acc[i][j] = __builtin_amdgcn_mfma_f32_16x16x32_bf16(af[i], bfr[j], acc[i][j], 0, 0, 0);
  }

  // epilogue: + bias, store bf16
  float bj[4];
#pragma unroll
  for (int j = 0; j < 4; ++j) bj[j] = biasp[cb + j * 16 + l16];
#pragma unroll
  for (int i = 0; i < 8; ++i){
    int mrow = wave * 128 + i * 16 + quad * 4;
#pragma unroll
    for (int r = 0; r < 4; ++r){
      u16* orow = outp + (size_t)(mrow + r) * HFD + cb + l16;
#pragma unroll
      for (int j = 0; j < 4; ++j)
        orow[j * 16] = f2bf(acc[i][j][r] + bj[j]);
    }
  }
}

// ---------------- GATv2 edge logits (+ degree count fused) ------------------
// one block per edge, one wave per head
__global__ void k_logits(const int* __restrict__ ei, const u16* __restrict__ xl,
                         const u16* __restrict__ xr, const float* __restrict__ att,
                         float* __restrict__ logits, int* __restrict__ cnt){
  int e = blockIdx.x;
  int h = threadIdx.x >> 6, lane = threadIdx.x & 63;
  int s, d;
  if (e < E_IN){ s = ei[e]; d = ei[E_IN + e]; } else { s = e - E_IN; d = s; }
  if (threadIdx.x == 0) atomicAdd(&cnt[d], 1);
  const u16* xlp = xl + (size_t)s * HFD + h * FDIM;
  const u16* xrp = xr + (size_t)d * HFD + h * FDIM;
  const float* ap = att + h * FDIM;
  float acc = 0.f;
#pragma unroll
  for (int it = 0; it < 6; ++it){
    int f = it * 512 + lane * 8;
    uint4 a = *(const uint4*)(xlp + f);
    uint4 b = *(const uint4*)(xrp + f);
    float4 w0 = *(const float4*)(ap + f);
    float4 w1 = *(const float4*)(ap + f + 4);
    float v0 = bflo(a.x) + bflo(b.x); v0 = v0 > 0.f ? v0 : SLOPE * v0;
    float v1 = bfhi(a.x) + bfhi(b.x); v1 = v1 > 0.f ? v1 : SLOPE * v1;
    float v2 = bflo(a.y) + bflo(b.y); v2 = v2 > 0.f ? v2 : SLOPE * v2;
    float v3 = bfhi(a.y) + bfhi(b.y); v3 = v3 > 0.f ? v3 : SLOPE * v3;
    float v4 = bflo(a.z) + bflo(b.z); v4 = v4 > 0.f ? v4 : SLOPE * v4;
    float v5 = bfhi(a.z) + bfhi(b.z); v5 = v5 > 0.f ? v5 : SLOPE * v5;
    float v6 = bflo(a.w) + bflo(b.w); v6 = v6 > 0.f ? v6 : SLOPE * v6;
    float v7 = bfhi(a.w) + bfhi(b.w); v7 = v7 > 0.f ? v7 : SLOPE * v7;
    acc += v0 * w0.x + v1 * w0.y + v2 * w0.z + v3 * w0.w;
    acc += v4 * w1.x + v5 * w1.y + v6 * w1.z + v7 * w1.w;
  }
#pragma unroll
  for (int o = 32; o > 0; o >>= 1) acc += __shfl_down(acc, o);
  if (lane == 0) logits[e * 4 + h] = acc;
}

// ---------------- CSR build -------------------------------------------------
__global__ void k_scan(const int* __restrict__ cnt, int* __restrict__ off,
                       int* __restrict__ cursor){
  __shared__ int s[512];
  int t = threadIdx.x;
  int v = cnt[t];
  s[t] = v;
  __syncthreads();
  for (int d = 1; d < 512; d <<= 1){
    int add = (t >= d) ? s[t - d] : 0;
    __syncthreads();
    s[t] += add;
    __syncthreads();
  }
  int exc = s[t] - v;
  off[t] = exc;
  cursor[t] = exc;
}

__global__ void k_scatter(const int* __restrict__ ei, int* __restrict__ cursor,
                          int* __restrict__ elist){
  int e = blockIdx.x * 256 + threadIdx.x;
  if (e >= E_TOT) return;
  int d = (e < E_IN) ? ei[E_IN + e] : (e - E_IN);
  int pos = atomicAdd(&cursor[d], 1);
  elist[pos] = e;
}

// ---------------- per-dst segment softmax -> alpha -------------------------
__global__ void k_softmax(const int* __restrict__ cnt, const int* __restrict__ off,
                          const int* __restrict__ elist, const float* __restrict__ logits,
                          float* __restrict__ alpha){
  int i = blockIdx.x;
  int lane = threadIdx.x;            // block of 64 = 1 wave
  int deg = cnt[i], st = off[i];
#pragma unroll
  for (int h = 0; h < 4; ++h){
    float mx = -1e30f;
    for (int j = lane; j < deg; j += 64){
      int e = elist[st + j];
      mx = fmaxf(mx, logits[e * 4 + h]);
    }
#pragma unroll
    for (int o = 32; o > 0; o >>= 1) mx = fmaxf(mx, __shfl_down(mx, o));
    mx = __shfl(mx, 0);
    float sm = 0.f;
    for (int j = lane; j < deg; j += 64){
      int e = elist[st + j];
      sm += __expf(logits[e * 4 + h] - mx);
    }
#pragma unroll
    for (int o = 32; o > 0; o >>= 1) sm += __shfl_down(sm, o);
    sm = __shfl(sm, 0);
    float rs = 1.f / sm;
    for (int j = lane; j < deg; j += 64){
      int e = elist[st + j];
      alpha[e * 4 + h] = __expf(logits[e * 4 + h] - mx) * rs;
    }
  }
}

// ---------------- aggregate: agg[dst][h][f] = sum alpha * xl[src] ----------
__global__ void k_agg(const int* __restrict__ ei, const int* __restrict__ cnt,
                      const int* __restrict__ off, const int* __restrict__ elist,
                      const float* __restrict__ alpha, const u16* __restrict__ xl,
                      float* __restrict__ agg){
  int b = blockIdx.x;
  int dst = b >> 2, h = b & 3;
  int deg = cnt[dst], st = off[dst];
  int t = threadIdx.x;
#pragma unroll
  for (int c = 0; c < 3; ++c){
    int f = c * 1024 + t * 4;
    float a0 = 0.f, a1 = 0.f, a2 = 0.f, a3 = 0.f;
    for (int j = 0; j < deg; ++j){
      int e = elist[st + j];
      int s = (e < E_IN) ? ei[e] : (e - E_IN);
      float al = alpha[e * 4 + h];
      ushort4 xv = *(const ushort4*)(xl + (size_t)s * HFD + h * FDIM + f);
      a0 += al * bf2f(xv.x);
      a1 += al * bf2f(xv.y);
      a2 += al * bf2f(xv.z);
      a3 += al * bf2f(xv.w);
    }
    float4* op = (float4*)(agg + (size_t)dst * HFD + h * FDIM + f);
    *op = make_float4(a0, a1, a2, a3);
  }
}

// ---------------- fc2+BN2+shortcut + FFN (fused epilogue) ------------------
__global__ void k_final(const float* __restrict__ agg, const float* __restrict__ gat_b,
                        const float* __restrict__ W2, const float* __restrict__ b2,
                        const float* __restrict__ g2, const float* __restrict__ bb2,
                        const float* __restrict__ m2, const float* __restrict__ v2,
                        const float* __restrict__ W3, const float* __restrict__ b3,
                        const float* __restrict__ g3, const float* __restrict__ bb3,
                        const float* __restrict__ m3, const float* __restrict__ v3,
                        const float* __restrict__ W4, const float* __restrict__ b4,
                        const float* __restrict__ g4, const float* __restrict__ bb4,
                        const float* __restrict__ m4, const float* __restrict__ v4,
                        const float* __restrict__ x, float* __restrict__ out){
  int id = blockIdx.x * 256 + threadIdx.x;
  int n = id >> 10, p = id & 1023;
  float a[12];
#pragma unroll
  for (int o = 0; o < 12; ++o)
    a[o] = agg[(size_t)n * HFD + o * 1024 + p] + gat_b[o * 1024 + p];
  float g[3];
#pragma unroll
  for (int c = 0; c < 3; ++c){
    float t = b2[c];
#pragma unroll
    for (int o = 0; o < 12; ++o) t += W2[c * 12 + o] * a[o];
    float inv = g2[c] * rsqrtf(v2[c] + EPSV);
    g[c] = t * inv + (bb2[c] - m2[c] * inv) + x[n * FDIM + c * 1024 + p];
  }
  float f1[3];
#pragma unroll
  for (int c = 0; c < 3; ++c){
    float t = b3[c] + W3[c*3+0]*g[0] + W3[c*3+1]*g[1] + W3[c*3+2]*g[2];
    float inv = g3[c] * rsqrtf(v3[c] + EPSV);
    float vv = t * inv + (bb3[c] - m3[c] * inv);
    f1[c] = fmaxf(vv, 0.f);
  }
#pragma unroll
  for (int c = 0; c < 3; ++c){
    float t = b4[c] + W4[c*3+0]*f1[0] + W4[c*3+1]*f1[1] + W4[c*3+2]*f1[2];
    float inv = g4[c] * rsqrtf(v4[c] + EPSV);
    out[n * FDIM + c * 1024 + p] = t * inv + (bb4[c] - m4[c] * inv) + g[c];
  }
}

extern "C" void kernel_launch(void* const* d_in, const int* in_sizes, int n_in,
                              void* d_out, int out_size, void* d_ws, size_t ws_size,
                              hipStream_t stream){
  (void)in_sizes; (void)n_in; (void)out_size; (void)ws_size;
  const float* x     = (const float*)d_in[0];
  const int*   ei    = (const int*)d_in[1];
  const float* fc1_W = (const float*)d_in[2];
  const float* fc1_b = (const float*)d_in[3];
  const float* bn1_g = (const float*)d_in[4];
  const float* bn1_b = (const float*)d_in[5];
  const float* bn1_m = (const float*)d_in[6];
  const float* bn1_v = (const float*)d_in[7];
  const float* Wl    = (const float*)d_in[8];
  const float* bl    = (const float*)d_in[9];
  const float* Wr    = (const float*)d_in[10];
  const float* br    = (const float*)d_in[11];
  const float* att   = (const float*)d_in[12];
  const float* gat_b = (const float*)d_in[13];
  const float* fc2_W = (const float*)d_in[14];
  const float* fc2_b = (const float*)d_in[15];
  const float* bn2_g = (const float*)d_in[16];
  const float* bn2_b = (const float*)d_in[17];
  const float* bn2_m = (const float*)d_in[18];
  const float* bn2_v = (const float*)d_in[19];
  const float* ffn1_W= (const float*)d_in[20];
  const float* ffn1_b= (const float*)d_in[21];
  const float* bnf1_g= (const float*)d_in[22];
  const float* bnf1_b= (const float*)d_in[23];
  const float* bnf1_m= (const float*)d_in[24];
  const float* bnf1_v= (const float*)d_in[25];
  const float* ffn2_W= (const float*)d_in[26];
  const float* ffn2_b= (const float*)d_in[27];
  const float* bnf2_g= (const float*)d_in[28];
  const float* bnf2_b= (const float*)d_in[29];
  const float* bnf2_m= (const float*)d_in[30];
  const float* bnf2_v= (const float*)d_in[31];

  char* w = (char*)d_ws;
  u16*   hf     = (u16*)(w);                    // 512*3072*2      = 3,145,728
  u16*   xl     = (u16*)(w + 3145728);          // 512*12288*2     = 12,582,912
  u16*   xr     = (u16*)(w + 15728640);         // 12,582,912
  float* logits = (float*)(w + 28311552);       // 4608*4*4        = 73,728
  float* alpha  = (float*)(w + 28385280);       // 73,728
  int*   cnt    = (int*)(w + 28459008);         // 2048
  int*   offp   = (int*)(w + 28461056);         // 2048
  int*   cursor = (int*)(w + 28463104);         // 2048
  int*   elist  = (int*)(w + 28465152);         // 18,432
  float* agg    = (float*)(w + 28483584);       // 512*12288*4     = 25,165,824

  k_fc1<<<2048, 256, 0, stream>>>(x, fc1_W, fc1_b, bn1_g, bn1_b, bn1_m, bn1_v, hf, cnt);
  k_gemm<<<384, 256, 0, stream>>>(hf, Wl, bl, Wr, br, xl, xr);
  k_logits<<<E_TOT, 256, 0, stream>>>(ei, xl, xr, att, logits, cnt);
  k_scan<<<1, 512, 0, stream>>>(cnt, offp, cursor);
  k_scatter<<<18, 256, 0, stream>>>(ei, cursor, elist);
  k_softmax<<<512, 64, 0, stream>>>(cnt, offp, elist, logits, alpha);
  k_agg<<<2048, 256, 0, stream>>>(ei, cnt, offp, elist, alpha, xl, agg);
  k_final<<<2048, 256, 0, stream>>>(agg, gat_b, fc2_W, fc2_b, bn2_g, bn2_b, bn2_m, bn2_v,
                                    ffn1_W, ffn1_b, bnf1_g, bnf1_b, bnf1_m, bnf1_v,
                                    ffn2_W, ffn2_b, bnf2_g, bnf2_b, bnf2_m, bnf2_v,
                                    x, (float*)d_out);
}

// Round 3
// 527.062 us; speedup vs baseline: 1.7573x; 1.0500x over previous
//
#include <hip/hip_runtime.h>

#define N_NODES 512
#define FDIM    3072
#define HEADS   4
#define HFD     12288        // HEADS*FDIM
#define E_IN    4096
#define E_TOT   4608         // E_IN + N self loops
#define EPSV    1e-5f
#define SLOPE   0.2f

typedef unsigned short u16;
typedef unsigned int   u32;

typedef short s16x8 __attribute__((ext_vector_type(8)));
typedef float f32x4 __attribute__((ext_vector_type(4)));

__device__ __forceinline__ u16 f2bf(float f){
  u32 u = __builtin_bit_cast(u32, f);
  u = (u + 0x7fffu + ((u >> 16) & 1u)) >> 16;
  return (u16)u;
}
__device__ __forceinline__ float bf2f(u16 h){
  return __builtin_bit_cast(float, ((u32)h) << 16);
}
__device__ __forceinline__ float bflo(u32 p){
  return __builtin_bit_cast(float, p << 16);
}
__device__ __forceinline__ float bfhi(u32 p){
  return __builtin_bit_cast(float, p & 0xffff0000u);
}

// async global -> LDS, 16 bytes per lane, dest = wave-uniform base + lane*16
__device__ __forceinline__ void gl_lds16(const u16* g, u16* l){
  __builtin_amdgcn_global_load_lds(
      (const __attribute__((address_space(1))) unsigned int*)g,
      (__attribute__((address_space(3))) unsigned int*)l, 16, 0, 0);
}

// ---------------- fc1 (1x1 conv C=3) + BN1 -> hf bf16 [512][3072] ----------
__global__ void k_fc1(const float* __restrict__ x, const float* __restrict__ W,
                      const float* __restrict__ b, const float* __restrict__ g,
                      const float* __restrict__ bb, const float* __restrict__ m,
                      const float* __restrict__ v, u16* __restrict__ hf,
                      int* __restrict__ cnt){
  int id = blockIdx.x * 256 + threadIdx.x;   // 0..524287
  if (id < 512) cnt[id] = 0;                 // zero CSR counts for k_logits
  int n = id >> 10, p = id & 1023;
  float x0 = x[n * FDIM + p];
  float x1 = x[n * FDIM + 1024 + p];
  float x2 = x[n * FDIM + 2048 + p];
#pragma unroll
  for (int c = 0; c < 3; ++c){
    float t = b[c] + W[c*3+0]*x0 + W[c*3+1]*x1 + W[c*3+2]*x2;
    float inv = g[c] * rsqrtf(v[c] + EPSV);
    float o = t * inv + (bb[c] - m[c] * inv);
    hf[n * FDIM + c * 1024 + p] = f2bf(o);
  }
}

// ---------------- big GEMM: hf[512x3072] @ [Wl|Wr][3072x24576] + bias ------
// M-split x2: BM=256, BN=64, BK=32 -> 768 blocks = 3/CU for TLP latency hiding.
// Same-N pairs placed 8 ids apart -> same XCD -> B weight stream shared via L2.
// A via async global_load_lds (XOR-swizzled, double-buffered), B reg-prefetched
// fp32 -> bf16 into double-buffered LDS. ONE barrier per K-step.
__global__ __launch_bounds__(256, 3) void k_gemm(
    const u16* __restrict__ hf, const float* __restrict__ Wl,
    const float* __restrict__ bl, const float* __restrict__ Wr,
    const float* __restrict__ br, u16* __restrict__ xl, u16* __restrict__ xr){
  __shared__ u16 As[2][256 * 32];   // 16 KB per buf
  __shared__ u16 Bs[2][64 * 40];    // 5 KB per buf (pad 40)

  const int tid  = threadIdx.x;
  const int wave = tid >> 6, lane = tid & 63;
  const int quad = lane >> 4, l16 = lane & 15;

  const int g = blockIdx.x;
  const int ntile = (g >> 4) * 8 + (g & 7);   // 0..383
  const int mhalf = (g >> 3) & 1;             // pair (mhalf=0,1) is 8 ids apart
  const int n0 = ntile * 64;
  const int rbase = mhalf * 256;

  const float* Wg; const float* biasp; u16* outp; int cb;
  if (n0 < HFD){ Wg = Wl; biasp = bl; outp = xl; cb = n0; }
  else         { Wg = Wr; biasp = br; outp = xr; cb = n0 - HFD; }

  // A DMA source: instr i of wave w covers rows rbase + w*64 + i*16 .. +15.
  // lane L: row += (L>>2), stores logical chunk (L&3)^((L>>3)&3) at pos L&3.
  const u16* ga = hf + (size_t)(rbase + wave * 64 + (lane >> 2)) * FDIM
                     + (((lane & 3) ^ ((lane >> 3) & 3)) << 3);

  // B staging: thread -> (col bn, k-octet bkh), 8 fp32 each
  const int bn = tid & 63, bkh = tid >> 6;
  const float* gb = Wg + (size_t)bkh * 8 * HFD + (cb + bn);
  const int bwo = bn * 40 + bkh * 8;

  // fragment read offsets (u16 units)
  const int araw = (wave * 64 + l16) * 32 + ((quad ^ ((l16 >> 1) & 3)) << 3);
  const int brd  = l16 * 40 + quad * 8;

  f32x4 acc[4][4];
#pragma unroll
  for (int i = 0; i < 4; ++i)
#pragma unroll
    for (int j = 0; j < 4; ++j) acc[i][j] = (f32x4){0.f, 0.f, 0.f, 0.f};

  float bv[8];
#pragma unroll
  for (int j = 0; j < 8; ++j) bv[j] = gb[(size_t)j * HFD];
#pragma unroll
  for (int i = 0; i < 4; ++i)
    gl_lds16(ga + (size_t)i * 16 * FDIM, As[0] + (wave * 4 + i) * 512);
  {
    u32 p0 = (u32)f2bf(bv[0]) | ((u32)f2bf(bv[1]) << 16);
    u32 p1 = (u32)f2bf(bv[2]) | ((u32)f2bf(bv[3]) << 16);
    u32 p2 = (u32)f2bf(bv[4]) | ((u32)f2bf(bv[5]) << 16);
    u32 p3 = (u32)f2bf(bv[6]) | ((u32)f2bf(bv[7]) << 16);
    *(uint4*)(Bs[0] + bwo) = make_uint4(p0, p1, p2, p3);
  }
#pragma unroll
  for (int j = 0; j < 8; ++j) bv[j] = gb[(size_t)(32 + j) * HFD];
  __syncthreads();

#define GEMM_BODY(KS, CUR, NXT)                                               \
  {                                                                           \
    const int ksv = (KS);                                                     \
    if (ksv < 95){                                                            \
      _Pragma("unroll")                                                       \
      for (int i = 0; i < 4; ++i)                                             \
        gl_lds16(ga + (size_t)i * 16 * FDIM + (ksv + 1) * 32,                 \
                 As[NXT] + (wave * 4 + i) * 512);                             \
      u32 p0 = (u32)f2bf(bv[0]) | ((u32)f2bf(bv[1]) << 16);                   \
      u32 p1 = (u32)f2bf(bv[2]) | ((u32)f2bf(bv[3]) << 16);                   \
      u32 p2 = (u32)f2bf(bv[4]) | ((u32)f2bf(bv[5]) << 16);                   \
      u32 p3 = (u32)f2bf(bv[6]) | ((u32)f2bf(bv[7]) << 16);                   \
      *(uint4*)(Bs[NXT] + bwo) = make_uint4(p0, p1, p2, p3);                  \
      int kn = (ksv + 2 < 96 ? ksv + 2 : 95) * 32;                            \
      _Pragma("unroll")                                                       \
      for (int j = 0; j < 8; ++j) bv[j] = gb[(size_t)(kn + j) * HFD];         \
    }                                                                         \
    s16x8 af[4], bfr[4];                                                      \
    _Pragma("unroll")                                                         \
    for (int i = 0; i < 4; ++i)                                               \
      af[i] = __builtin_bit_cast(s16x8, *(const uint4*)(As[CUR] + araw + i * 512)); \
    _Pragma("unroll")                                                         \
    for (int j = 0; j < 4; ++j)                                               \
      bfr[j] = __builtin_bit_cast(s16x8, *(const uint4*)(Bs[CUR] + brd + j * 640)); \
    _Pragma("unroll")                                                         \
    for (int i = 0; i < 4; ++i)                                               \
      _Pragma("unroll")                                                       \
      for (int j = 0; j < 4; ++j)                                             \
        acc[i][j] = __builtin_amdgcn_mfma_f32_16x16x32_bf16(af[i], bfr[j], acc[i][j], 0, 0, 0); \
    __syncthreads();                                                          \
  }

  for (int ks = 0; ks < 96; ks += 2){
    GEMM_BODY(ks, 0, 1);
    GEMM_BODY(ks + 1, 1, 0);
  }
#undef GEMM_BODY

  // epilogue: + bias, store bf16
  float bj[4];
#pragma unroll
  for (int j = 0; j < 4; ++j) bj[j] = biasp[cb + j * 16 + l16];
#pragma unroll
  for (int i = 0; i < 4; ++i){
    int mrow = rbase + wave * 64 + i * 16 + quad * 4;
#pragma unroll
    for (int r = 0; r < 4; ++r){
      u16* orow = outp + (size_t)(mrow + r) * HFD + cb + l16;
#pragma unroll
      for (int j = 0; j < 4; ++j)
        orow[j * 16] = f2bf(acc[i][j][r] + bj[j]);
    }
  }
}

// ---------------- GATv2 edge logits (+ degree count fused) ------------------
__global__ void k_logits(const int* __restrict__ ei, const u16* __restrict__ xl,
                         const u16* __restrict__ xr, const float* __restrict__ att,
                         float* __restrict__ logits, int* __restrict__ cnt){
  int e = blockIdx.x;
  int h = threadIdx.x >> 6, lane = threadIdx.x & 63;
  int s, d;
  if (e < E_IN){ s = ei[e]; d = ei[E_IN + e]; } else { s = e - E_IN; d = s; }
  if (threadIdx.x == 0) atomicAdd(&cnt[d], 1);
  const u16* xlp = xl + (size_t)s * HFD + h * FDIM;
  const u16* xrp = xr + (size_t)d * HFD + h * FDIM;
  const float* ap = att + h * FDIM;
  float acc = 0.f;
#pragma unroll
  for (int it = 0; it < 6; ++it){
    int f = it * 512 + lane * 8;
    uint4 a = *(const uint4*)(xlp + f);
    uint4 b = *(const uint4*)(xrp + f);
    float4 w0 = *(const float4*)(ap + f);
    float4 w1 = *(const float4*)(ap + f + 4);
    float v0 = bflo(a.x) + bflo(b.x); v0 = v0 > 0.f ? v0 : SLOPE * v0;
    float v1 = bfhi(a.x) + bfhi(b.x); v1 = v1 > 0.f ? v1 : SLOPE * v1;
    float v2 = bflo(a.y) + bflo(b.y); v2 = v2 > 0.f ? v2 : SLOPE * v2;
    float v3 = bfhi(a.y) + bfhi(b.y); v3 = v3 > 0.f ? v3 : SLOPE * v3;
    float v4 = bflo(a.z) + bflo(b.z); v4 = v4 > 0.f ? v4 : SLOPE * v4;
    float v5 = bfhi(a.z) + bfhi(b.z); v5 = v5 > 0.f ? v5 : SLOPE * v5;
    float v6 = bflo(a.w) + bflo(b.w); v6 = v6 > 0.f ? v6 : SLOPE * v6;
    float v7 = bfhi(a.w) + bfhi(b.w); v7 = v7 > 0.f ? v7 : SLOPE * v7;
    acc += v0 * w0.x + v1 * w0.y + v2 * w0.z + v3 * w0.w;
    acc += v4 * w1.x + v5 * w1.y + v6 * w1.z + v7 * w1.w;
  }
#pragma unroll
  for (int o = 32; o > 0; o >>= 1) acc += __shfl_down(acc, o);
  if (lane == 0) logits[e * 4 + h] = acc;
}

// ---------------- CSR build: scan + scatter in one single-block kernel -----
__global__ void k_scan_scatter(const int* __restrict__ ei, const int* __restrict__ cnt,
                               int* __restrict__ off, int* __restrict__ elist){
  __shared__ int s[512];
  __shared__ int cur[512];
  int t = threadIdx.x;
  int v = cnt[t];
  s[t] = v;
  __syncthreads();
  for (int d = 1; d < 512; d <<= 1){
    int add = (t >= d) ? s[t - d] : 0;
    __syncthreads();
    s[t] += add;
    __syncthreads();
  }
  int exc = s[t] - v;
  off[t] = exc;
  cur[t] = exc;
  __syncthreads();
  for (int e = t; e < E_TOT; e += 512){
    int d = (e < E_IN) ? ei[E_IN + e] : (e - E_IN);
    int pos = atomicAdd(&cur[d], 1);
    elist[pos] = e;
  }
}

// ---------------- per-dst segment softmax -> alpha -------------------------
__global__ void k_softmax(const int* __restrict__ cnt, const int* __restrict__ off,
                          const int* __restrict__ elist, const float* __restrict__ logits,
                          float* __restrict__ alpha){
  int i = blockIdx.x;
  int lane = threadIdx.x;            // block of 64 = 1 wave
  int deg = cnt[i], st = off[i];
#pragma unroll
  for (int h = 0; h < 4; ++h){
    float mx = -1e30f;
    for (int j = lane; j < deg; j += 64){
      int e = elist[st + j];
      mx = fmaxf(mx, logits[e * 4 + h]);
    }
#pragma unroll
    for (int o = 32; o > 0; o >>= 1) mx = fmaxf(mx, __shfl_down(mx, o));
    mx = __shfl(mx, 0);
    float sm = 0.f;
    for (int j = lane; j < deg; j += 64){
      int e = elist[st + j];
      sm += __expf(logits[e * 4 + h] - mx);
    }
#pragma unroll
    for (int o = 32; o > 0; o >>= 1) sm += __shfl_down(sm, o);
    sm = __shfl(sm, 0);
    float rs = 1.f / sm;
    for (int j = lane; j < deg; j += 64){
      int e = elist[st + j];
      alpha[e * 4 + h] = __expf(logits[e * 4 + h] - mx) * rs;
    }
  }
}

// ---------------- fused aggregate + fc2/BN2/shortcut + FFN -----------------
// block = dst node; acc[12 channels][4 pixels] in registers; no agg buffer.
__global__ __launch_bounds__(256) void k_aggfinal(
    const int* __restrict__ ei, const int* __restrict__ cnt,
    const int* __restrict__ off, const int* __restrict__ elist,
    const float* __restrict__ alpha, const u16* __restrict__ xl,
    const float* __restrict__ gat_b,
    const float* __restrict__ W2, const float* __restrict__ b2,
    const float* __restrict__ g2, const float* __restrict__ bb2,
    const float* __restrict__ m2, const float* __restrict__ v2,
    const float* __restrict__ W3, const float* __restrict__ b3,
    const float* __restrict__ g3, const float* __restrict__ bb3,
    const float* __restrict__ m3, const float* __restrict__ v3,
    const float* __restrict__ W4, const float* __restrict__ b4,
    const float* __restrict__ g4, const float* __restrict__ bb4,
    const float* __restrict__ m4, const float* __restrict__ v4,
    const float* __restrict__ x, float* __restrict__ out){
  __shared__ int    s_src[128];
  __shared__ float4 s_al[128];
  const int n = blockIdx.x;
  const int t = threadIdx.x;
  const int p4 = t * 4;
  const int deg = cnt[n], st = off[n];

  float acc[12][4];
#pragma unroll
  for (int o = 0; o < 12; ++o)
#pragma unroll
    for (int r = 0; r < 4; ++r) acc[o][r] = 0.f;

  for (int base = 0; base < deg; base += 128){
    int cn = min(deg - base, 128);
    if (t < cn){
      int e = elist[st + base + t];
      s_src[t] = (e < E_IN) ? ei[e] : (e - E_IN);
      s_al[t] = *(const float4*)(alpha + e * 4);
    }
    __syncthreads();
    for (int j = 0; j < cn; ++j){
      int s = s_src[j];
      float4 al4 = s_al[j];
      float alh[4] = {al4.x, al4.y, al4.z, al4.w};
      const u16* bp = xl + (size_t)s * HFD;
#pragma unroll
      for (int h = 0; h < 4; ++h){
#pragma unroll
        for (int c = 0; c < 3; ++c){
          ushort4 xv = *(const ushort4*)(bp + h * FDIM + c * 1024 + p4);
          acc[h*3+c][0] += alh[h] * bf2f(xv.x);
          acc[h*3+c][1] += alh[h] * bf2f(xv.y);
          acc[h*3+c][2] += alh[h] * bf2f(xv.z);
          acc[h*3+c][3] += alh[h] * bf2f(xv.w);
        }
      }
    }
    __syncthreads();
  }

  // + gat bias
#pragma unroll
  for (int o = 0; o < 12; ++o){
    float4 gv = *(const float4*)(gat_b + o * 1024 + p4);
    acc[o][0] += gv.x; acc[o][1] += gv.y; acc[o][2] += gv.z; acc[o][3] += gv.w;
  }
  // shortcut x
  float xv[3][4];
#pragma unroll
  for (int c = 0; c < 3; ++c){
    float4 t4 = *(const float4*)(x + (size_t)n * FDIM + c * 1024 + p4);
    xv[c][0] = t4.x; xv[c][1] = t4.y; xv[c][2] = t4.z; xv[c][3] = t4.w;
  }
  float o4[3][4];
#pragma unroll
  for (int r = 0; r < 4; ++r){
    float gch[3];
#pragma unroll
    for (int c = 0; c < 3; ++c){
      float tt = b2[c];
#pragma unroll
      for (int o = 0; o < 12; ++o) tt += W2[c * 12 + o] * acc[o][r];
      float inv = g2[c] * rsqrtf(v2[c] + EPSV);
      gch[c] = tt * inv + (bb2[c] - m2[c] * inv) + xv[c][r];
    }
    float f1[3];
#pragma unroll
    for (int c = 0; c < 3; ++c){
      float tt = b3[c] + W3[c*3+0]*gch[0] + W3[c*3+1]*gch[1] + W3[c*3+2]*gch[2];
      float inv = g3[c] * rsqrtf(v3[c] + EPSV);
      float vv = tt * inv + (bb3[c] - m3[c] * inv);
      f1[c] = fmaxf(vv, 0.f);
    }
#pragma unroll
    for (int c = 0; c < 3; ++c){
      float tt = b4[c] + W4[c*3+0]*f1[0] + W4[c*3+1]*f1[1] + W4[c*3+2]*f1[2];
      float inv = g4[c] * rsqrtf(v4[c] + EPSV);
      o4[c][r] = tt * inv + (bb4[c] - m4[c] * inv) + gch[c];
    }
  }
#pragma unroll
  for (int c = 0; c < 3; ++c)
    *(float4*)(out + (size_t)n * FDIM + c * 1024 + p4) =
        make_float4(o4[c][0], o4[c][1], o4[c][2], o4[c][3]);
}

extern "C" void kernel_launch(void* const* d_in, const int* in_sizes, int n_in,
                              void* d_out, int out_size, void* d_ws, size_t ws_size,
                              hipStream_t stream){
  (void)in_sizes; (void)n_in; (void)out_size; (void)ws_size;
  const float* x     = (const float*)d_in[0];
  const int*   ei    = (const int*)d_in[1];
  const float* fc1_W = (const float*)d_in[2];
  const float* fc1_b = (const float*)d_in[3];
  const float* bn1_g = (const float*)d_in[4];
  const float* bn1_b = (const float*)d_in[5];
  const float* bn1_m = (const float*)d_in[6];
  const float* bn1_v = (const float*)d_in[7];
  const float* Wl    = (const float*)d_in[8];
  const float* bl    = (const float*)d_in[9];
  const float* Wr    = (const float*)d_in[10];
  const float* br    = (const float*)d_in[11];
  const float* att   = (const float*)d_in[12];
  const float* gat_b = (const float*)d_in[13];
  const float* fc2_W = (const float*)d_in[14];
  const float* fc2_b = (const float*)d_in[15];
  const float* bn2_g = (const float*)d_in[16];
  const float* bn2_b = (const float*)d_in[17];
  const float* bn2_m = (const float*)d_in[18];
  const float* bn2_v = (const float*)d_in[19];
  const float* ffn1_W= (const float*)d_in[20];
  const float* ffn1_b= (const float*)d_in[21];
  const float* bnf1_g= (const float*)d_in[22];
  const float* bnf1_b= (const float*)d_in[23];
  const float* bnf1_m= (const float*)d_in[24];
  const float* bnf1_v= (const float*)d_in[25];
  const float* ffn2_W= (const float*)d_in[26];
  const float* ffn2_b= (const float*)d_in[27];
  const float* bnf2_g= (const float*)d_in[28];
  const float* bnf2_b= (const float*)d_in[29];
  const float* bnf2_m= (const float*)d_in[30];
  const float* bnf2_v= (const float*)d_in[31];

  char* w = (char*)d_ws;
  u16*   hf     = (u16*)(w);                    // 3,145,728
  u16*   xl     = (u16*)(w + 3145728);          // 12,582,912
  u16*   xr     = (u16*)(w + 15728640);         // 12,582,912
  float* logits = (float*)(w + 28311552);       // 73,728
  float* alpha  = (float*)(w + 28385280);       // 73,728
  int*   cnt    = (int*)(w + 28459008);         // 2048
  int*   offp   = (int*)(w + 28461056);         // 2048
  int*   elist  = (int*)(w + 28465152);         // 18,432

  k_fc1<<<2048, 256, 0, stream>>>(x, fc1_W, fc1_b, bn1_g, bn1_b, bn1_m, bn1_v, hf, cnt);
  k_gemm<<<768, 256, 0, stream>>>(hf, Wl, bl, Wr, br, xl, xr);
  k_logits<<<E_TOT, 256, 0, stream>>>(ei, xl, xr, att, logits, cnt);
  k_scan_scatter<<<1, 512, 0, stream>>>(ei, cnt, offp, elist);
  k_softmax<<<512, 64, 0, stream>>>(cnt, offp, elist, logits, alpha);
  k_aggfinal<<<512, 256, 0, stream>>>(ei, cnt, offp, elist, alpha, xl, gat_b,
                                      fc2_W, fc2_b, bn2_g, bn2_b, bn2_m, bn2_v,
                                      ffn1_W, ffn1_b, bnf1_g, bnf1_b, bnf1_m, bnf1_v,
                                      ffn2_W, ffn2_b, bnf2_g, bnf2_b, bnf2_m, bnf2_v,
                                      x, (float*)d_out);
}